// Round 10
// baseline (245.741 us; speedup 1.0000x reference)
//
#include <hip/hip_runtime.h>
#include <hip/hip_bf16.h>
#include <hip/hip_fp16.h>

// Problem constants
#define DM   256
#define NH   8
#define HC   32
#define SEQ  512
#define MTOT 1024

// ---------- workspace layout (byte offsets) ----------
#define B_X1B  0            // bf16 x1 [1024][256]      512 KB
#define B_QH   (1u<<20)     // fp16 q  [16][512][32]    512 KB
#define B_KH   0x180000u    // fp16 k  [16][512][32]    512 KB
#define B_VT   0x200000u    // bf16 vT [16][32][512]    512 KB
#define B_WFCT 0x280000u    // bf16 WfcT  [1024][256]   512 KB
#define B_WPJT 0x300000u    // bf16 WprojT [256][1024]  512 KB
#define B_CTR  0x380000u    // u32 attn-done counter (init by K1)

typedef __attribute__((ext_vector_type(8))) __bf16 bf16x8;
typedef __attribute__((ext_vector_type(4))) __bf16 bf16x4;
typedef __attribute__((ext_vector_type(4))) float  f32x4;

__device__ __forceinline__ float qgelu(float x) {
    return x / (1.0f + __expf(-1.702f * x));
}

// ---------------------------------------------------------------------------
// K1: QKV GEMM (1024x768, K=256) + side-car weight transposes (round-8 form)
// + init of the K2 producer/consumer counter (stream order makes it visible).
// ---------------------------------------------------------------------------
__global__ __launch_bounds__(256)
void qkv_k(const float* __restrict__ x, const float* __restrict__ W,
           const float* __restrict__ bias,
           const float* __restrict__ Wfc, const float* __restrict__ Wproj,
           char* __restrict__ wsb)
{
    __shared__ float lt[64 * 65];
    const int bid = blockIdx.x, tid = threadIdx.x;

    if (bid == 0 && tid == 0) *(unsigned*)(wsb + B_CTR) = 0u;   // flag init

    if (bid >= 768) {
        const int tt = bid - 768;
        const float* src; __bf16* dst; int K, N, tile;
        if (tt < 64) { src = Wfc;   dst = (__bf16*)(wsb + B_WFCT); K = 256;  N = 1024; tile = tt; }
        else         { src = Wproj; dst = (__bf16*)(wsb + B_WPJT); K = 1024; N = 256;  tile = tt - 64; }
        const int nn = N >> 6;
        const int k0 = (tile / nn) * 64, n0 = (tile % nn) * 64;
        const int rr0 = tid >> 4, c4 = tid & 15;
        #pragma unroll
        for (int i = 0; i < 4; ++i) {
            const int rr = rr0 + i * 16;
            float4 v = *(const float4*)&src[(size_t)(k0 + rr) * N + n0 + c4 * 4];
            lt[rr * 65 + c4 * 4 + 0] = v.x; lt[rr * 65 + c4 * 4 + 1] = v.y;
            lt[rr * 65 + c4 * 4 + 2] = v.z; lt[rr * 65 + c4 * 4 + 3] = v.w;
        }
        __syncthreads();
        #pragma unroll
        for (int i = 0; i < 4; ++i) {
            const int rr = rr0 + i * 16;
            bf16x4 b;
            b.x = (__bf16)lt[(c4 * 4 + 0) * 65 + rr];
            b.y = (__bf16)lt[(c4 * 4 + 1) * 65 + rr];
            b.z = (__bf16)lt[(c4 * 4 + 2) * 65 + rr];
            b.w = (__bf16)lt[(c4 * 4 + 3) * 65 + rr];
            *(bf16x4*)&dst[(size_t)(n0 + rr) * K + k0 + c4 * 4] = b;
        }
        return;
    }

    const int lane = tid & 63, wv = tid >> 6;
    const int widx = bid * 4 + wv;               // 0..3071
    const int m0 = (widx & 63) * 16, n0 = (widx >> 6) * 16;
    const int r = lane & 15, q = lane >> 4;

    const float* ap = x + (size_t)(m0 + r) * DM + q * 8;
    const float* bp = W + (size_t)(q * 8) * 768 + n0 + r;

    f32x4 acc = {0.f, 0.f, 0.f, 0.f};
    #pragma unroll
    for (int kt = 0; kt < DM; kt += 32) {
        float4 a0 = *(const float4*)(ap + kt);
        float4 a1 = *(const float4*)(ap + kt + 4);
        bf16x8 af;
        af[0] = (__bf16)a0.x; af[1] = (__bf16)a0.y; af[2] = (__bf16)a0.z; af[3] = (__bf16)a0.w;
        af[4] = (__bf16)a1.x; af[5] = (__bf16)a1.y; af[6] = (__bf16)a1.z; af[7] = (__bf16)a1.w;
        bf16x8 bf;
        #pragma unroll
        for (int j = 0; j < 8; ++j)
            bf[j] = (__bf16)bp[(size_t)(kt + j) * 768];
        acc = __builtin_amdgcn_mfma_f32_16x16x32_bf16(af, bf, acc, 0, 0, 0);
    }

    __half*  qh  = (__half*)(wsb + B_QH);
    __half*  kh  = (__half*)(wsb + B_KH);
    __bf16*  vtb = (__bf16*)(wsb + B_VT);
    const int n = n0 + r;                 // C col = lane&15
    const float bn = bias[n];
    const int h = n / 96, jj = n % 96;
    #pragma unroll
    for (int i = 0; i < 4; ++i) {
        const int m = m0 + q * 4 + i;     // C row = q*4 + i
        const float v = acc[i] + bn;
        const int b = m >> 9, t = m & 511;
        const int bh = b * NH + h;
        if (jj < 32)      qh[((size_t)(bh * SEQ + t)) * HC + jj]        = (__half)v;
        else if (jj < 64) kh[((size_t)(bh * SEQ + t)) * HC + (jj - 32)] = (__half)v;
        else              vtb[((size_t)(bh * HC + (jj - 64))) * SEQ + t] = (__bf16)v;
    }
}

// ---------------------------------------------------------------------------
// K2: fused attention + MLP, flag-synced (one launch).
// Blocks 0..511:  L1-distance attention (fp16-packed dist) + residual;
//                 epilogue x1 bf16 + out = x1 + bproj; release-add ctr.
// Blocks 512..767: spin (acquire) until ctr==512, then split-K MLP:
//                 h-slab -> LDS; partial @ Wproj k-slice -> atomicAdd out.
// Deadlock-free: producers never wait; consumers always leave slots free.
// ---------------------------------------------------------------------------
#define QT 16
#define PSTRIDE 514
#define HSTR 264
// smem layout (bytes): pmat 0..16448 | qtile 16448..17472 | psum ..17984 | pinv ..18048
// mlp: hs at 0 (8448 B)

__global__ __launch_bounds__(512, 2)
void attn_mlp_k(char* __restrict__ wsb, const float* __restrict__ xin,
                const float* __restrict__ bproj, const float* __restrict__ bfc,
                float* __restrict__ out)
{
    __shared__ __align__(16) char smem[18048];
    unsigned* ctr = (unsigned*)(wsb + B_CTR);
    const int tid = threadIdx.x;
    const int lane = tid & 63;
    const int wv   = tid >> 6;

    if (blockIdx.x < 512) {
        // ======================= attention =======================
        __bf16*  pmat  = (__bf16*)smem;
        __half2* qtile = (__half2*)(smem + 16448);
        float*   psum  = (float*)(smem + 17472);
        float*   pinv  = (float*)(smem + 17984);

        const __half* qhg = (const __half*)(wsb + B_QH);
        const __half* khg = (const __half*)(wsb + B_KH);
        const __bf16* vtb = (const __bf16*)(wsb + B_VT);
        __bf16*       x1b = (__bf16*)(wsb + B_X1B);

        const int sg   = tid;                       // s index
        const int bh   = blockIdx.x >> 5;
        const int qbase = (blockIdx.x & 31) * QT;
        const float scale = 0.17677669529663687f;   // 1/sqrt(32)

        const __half2* kp = (const __half2*)(khg + ((size_t)(bh * SEQ + sg)) * HC);
        __half2 kr[16];
        #pragma unroll
        for (int j = 0; j < 16; ++j) kr[j] = kp[j];

        if (tid < 256) {
            const int t = tid >> 4, j = tid & 15;
            qtile[t * 16 + j] =
                *(const __half2*)(qhg + ((size_t)(bh * SEQ + qbase + t)) * HC + j * 2);
        }
        __syncthreads();

        #pragma unroll 4
        for (int t = 0; t < QT; ++t) {
            __half2 a0 = __floats2half2_rn(0.f, 0.f), a1 = a0;
            #pragma unroll
            for (int j = 0; j < 16; j += 2) {
                __half2 d0 = __hsub2(kr[j],   qtile[t * 16 + j]);
                __half2 d1 = __hsub2(kr[j+1], qtile[t * 16 + j + 1]);
                unsigned u0 = (*(unsigned*)&d0) & 0x7FFF7FFFu;
                unsigned u1 = (*(unsigned*)&d1) & 0x7FFF7FFFu;
                a0 = __hadd2(a0, *(__half2*)&u0);
                a1 = __hadd2(a1, *(__half2*)&u1);
            }
            __half2 acc2 = __hadd2(a0, a1);
            const float d = __low2float(acc2) + __high2float(acc2);
            float w = 1.0f / (0.001f + d * scale);
            if (sg == qbase + t) w = 0.0f;          // diagonal
            float p = __expf(w);                    // w bounded: no max pass
            float se = p;
            #pragma unroll
            for (int off = 32; off >= 1; off >>= 1) se += __shfl_xor(se, off, 64);
            pmat[t * PSTRIDE + sg] = (__bf16)p;
            if (lane == 0) psum[t * 8 + wv] = se;
        }
        __syncthreads();

        if (tid < QT) {
            float s = 0.f;
            #pragma unroll
            for (int j = 0; j < 8; ++j) s += psum[tid * 8 + j];
            pinv[tid] = 1.0f / s;
        }
        __syncthreads();

        if (wv < 2) {
            const int r = lane & 15, q = lane >> 4;
            const __bf16* bp  = vtb + ((size_t)(bh * HC + wv * 16 + r)) * SEQ + q * 8;
            const __bf16* apm = &pmat[r * PSTRIDE + q * 8];
            f32x4 acc = {0.f, 0.f, 0.f, 0.f};
            #pragma unroll
            for (int kt = 0; kt < SEQ; kt += 32) {
                bf16x8 af = *(const bf16x8*)(apm + kt);
                bf16x8 bf = *(const bf16x8*)(bp + kt);
                acc = __builtin_amdgcn_mfma_f32_16x16x32_bf16(af, bf, acc, 0, 0, 0);
            }
            const int b = bh >> 3, hh = bh & 7;
            const int c = wv * 16 + r;
            const int col = hh * HC + c;
            const float bpn = bproj[col];
            #pragma unroll
            for (int i = 0; i < 4; ++i) {
                const int tl = q * 4 + i;
                const int t  = qbase + tl;
                const float v = acc[i] * pinv[tl];
                const int idx = ((b * SEQ + t) * DM) + col;
                const float res = xin[idx] + v;
                x1b[idx] = (__bf16)res;
                out[idx] = res + bpn;      // base; MLP atomically adds h@Wproj
            }
        }

        __threadfence();
        __syncthreads();
        if (tid == 0)
            __hip_atomic_fetch_add(ctr, 1u, __ATOMIC_RELEASE, __HIP_MEMORY_SCOPE_AGENT);
        return;
    }

    // ======================= MLP (consumer) =======================
    if (tid == 0) {
        unsigned it = 0;
        while (__hip_atomic_load(ctr, __ATOMIC_ACQUIRE, __HIP_MEMORY_SCOPE_AGENT) < 512u) {
            __builtin_amdgcn_s_sleep(16);
            if (++it > (1u << 24)) break;   // safety hatch (never expected)
        }
    }
    __syncthreads();
    __threadfence();

    __bf16* hs = (__bf16*)smem;   // [16][HSTR]
    const __bf16* X1B = (const __bf16*)(wsb + B_X1B);
    const __bf16* Wf  = (const __bf16*)(wsb + B_WFCT);
    const __bf16* Wp  = (const __bf16*)(wsb + B_WPJT);

    const int bid2 = blockIdx.x - 512;           // 0..255
    const int mt   = bid2 & 63;
    const int ns   = bid2 >> 6;                  // k/n slab 0..3
    const int m0   = mt * 16;
    const int r    = lane & 15, q = lane >> 4;

    // ---- FC phase: h[16][ns*256 .. +256), 8 waves x 2 n-tiles ----
    {
        const __bf16* ap = X1B + (size_t)(m0 + r) * DM + q * 8;
        f32x4 acc[2] = {};
        #pragma unroll
        for (int kt = 0; kt < DM; kt += 32) {
            bf16x8 af = *(const bf16x8*)(ap + kt);
            #pragma unroll
            for (int nt = 0; nt < 2; ++nt) {
                const int n0g = ns * 256 + (wv * 2 + nt) * 16;      // global h col
                bf16x8 bf = *(const bf16x8*)(Wf + (size_t)(n0g + r) * DM + q * 8 + kt);
                acc[nt] = __builtin_amdgcn_mfma_f32_16x16x32_bf16(af, bf, acc[nt], 0, 0, 0);
            }
        }
        #pragma unroll
        for (int nt = 0; nt < 2; ++nt) {
            const int nl = (wv * 2 + nt) * 16 + r;                  // local 0..255
            const float bn = bfc[ns * 256 + nl];
            #pragma unroll
            for (int i = 0; i < 4; ++i)
                hs[(q * 4 + i) * HSTR + nl] = (__bf16)qgelu(acc[nt][i] + bn);
        }
    }
    __syncthreads();

    // ---- PROJ phase: out[m0..+16][...] += h_slab @ Wp k-slice ----
    {
        f32x4 acc[2] = {};
        const __bf16* al = &hs[r * HSTR + q * 8];                   // A row = m
        #pragma unroll
        for (int kt = 0; kt < 256; kt += 32) {
            bf16x8 af = *(const bf16x8*)(al + kt);
            #pragma unroll
            for (int nt = 0; nt < 2; ++nt) {
                const int n0 = (wv * 2 + nt) * 16;
                bf16x8 bf = *(const bf16x8*)(Wp + (size_t)(n0 + r) * 1024 +
                                             ns * 256 + q * 8 + kt);
                acc[nt] = __builtin_amdgcn_mfma_f32_16x16x32_bf16(af, bf, acc[nt], 0, 0, 0);
            }
        }
        #pragma unroll
        for (int nt = 0; nt < 2; ++nt) {
            const int n = (wv * 2 + nt) * 16 + r;
            #pragma unroll
            for (int i = 0; i < 4; ++i) {
                const int m = m0 + q * 4 + i;
                atomicAdd(&out[(size_t)m * DM + n], acc[nt][i]);
            }
        }
    }
}

// ---------------------------------------------------------------------------
extern "C" void kernel_launch(void* const* d_in, const int* in_sizes, int n_in,
                              void* d_out, int out_size, void* d_ws, size_t ws_size,
                              hipStream_t stream)
{
    (void)in_sizes; (void)n_in; (void)out_size; (void)ws_size;
    const float* x     = (const float*)d_in[0];
    const float* Wqkv  = (const float*)d_in[1];
    const float* bqkv  = (const float*)d_in[2];
    const float* Wfc   = (const float*)d_in[3];
    const float* bfc   = (const float*)d_in[4];
    const float* Wproj = (const float*)d_in[5];
    const float* bproj = (const float*)d_in[6];
    float* out = (float*)d_out;
    char*  wsb = (char*)d_ws;

    // K1: QKV GEMM + side-car transposes + ctr=0
    qkv_k<<<896, 256, 0, stream>>>(x, Wqkv, bqkv, Wfc, Wproj, wsb);

    // K2: attention (producers) + MLP (consumers), flag-synced in one launch
    attn_mlp_k<<<768, 512, 0, stream>>>(wsb, x, bproj, bfc, out);
}

// Round 11
// 106.137 us; speedup vs baseline: 2.3153x; 2.3153x over previous
//
#include <hip/hip_runtime.h>
#include <hip/hip_bf16.h>
#include <hip/hip_fp16.h>

// Problem constants
#define DM   256
#define NH   8
#define HC   32
#define SEQ  512
#define MTOT 1024

// ---------- workspace layout (byte offsets) ----------
#define B_X1   0            // fp32 x1 [1024][256]      1 MB
#define B_QH   (1u<<20)     // fp16 q  [16][512][32]    512 KB
#define B_KH   0x180000u    // fp16 k  [16][512][32]    512 KB
#define B_VT   0x200000u    // bf16 vT [16][32][512]    512 KB
#define B_WFCT 0x280000u    // bf16 WfcT  [1024][256]   512 KB
#define B_WPJT 0x300000u    // bf16 WprojT [256][1024]  512 KB

typedef __attribute__((ext_vector_type(8))) __bf16 bf16x8;
typedef __attribute__((ext_vector_type(4))) __bf16 bf16x4;
typedef __attribute__((ext_vector_type(4))) float  f32x4;

__device__ __forceinline__ float qgelu(float x) {
    return x / (1.0f + __expf(-1.702f * x));
}

// ---------------------------------------------------------------------------
// K1: QKV GEMM (1024x768, K=256) + side-car weight transposes (round-6/8 proven).
// Blocks 0..767: one 16x16 MFMA tile per wave. A = fp32 x cvt in-reg;
// B = strided fp32 loads from W_qkv. Epilogue: +bias, q/k fp16, v bf16 V^T.
// Blocks 768..895: LDS-tiled 64x64 transposes of Wfc/Wproj -> bf16 [n][k].
// ---------------------------------------------------------------------------
__global__ __launch_bounds__(256)
void qkv_k(const float* __restrict__ x, const float* __restrict__ W,
           const float* __restrict__ bias,
           const float* __restrict__ Wfc, const float* __restrict__ Wproj,
           char* __restrict__ wsb)
{
    __shared__ float lt[64 * 65];
    const int bid = blockIdx.x, tid = threadIdx.x;

    if (bid >= 768) {
        const int tt = bid - 768;
        const float* src; __bf16* dst; int K, N, tile;
        if (tt < 64) { src = Wfc;   dst = (__bf16*)(wsb + B_WFCT); K = 256;  N = 1024; tile = tt; }
        else         { src = Wproj; dst = (__bf16*)(wsb + B_WPJT); K = 1024; N = 256;  tile = tt - 64; }
        const int nn = N >> 6;
        const int k0 = (tile / nn) * 64, n0 = (tile % nn) * 64;
        const int rr0 = tid >> 4, c4 = tid & 15;
        #pragma unroll
        for (int i = 0; i < 4; ++i) {
            const int rr = rr0 + i * 16;
            float4 v = *(const float4*)&src[(size_t)(k0 + rr) * N + n0 + c4 * 4];
            lt[rr * 65 + c4 * 4 + 0] = v.x; lt[rr * 65 + c4 * 4 + 1] = v.y;
            lt[rr * 65 + c4 * 4 + 2] = v.z; lt[rr * 65 + c4 * 4 + 3] = v.w;
        }
        __syncthreads();
        #pragma unroll
        for (int i = 0; i < 4; ++i) {
            const int rr = rr0 + i * 16;
            bf16x4 b;
            b.x = (__bf16)lt[(c4 * 4 + 0) * 65 + rr];
            b.y = (__bf16)lt[(c4 * 4 + 1) * 65 + rr];
            b.z = (__bf16)lt[(c4 * 4 + 2) * 65 + rr];
            b.w = (__bf16)lt[(c4 * 4 + 3) * 65 + rr];
            *(bf16x4*)&dst[(size_t)(n0 + rr) * K + k0 + c4 * 4] = b;
        }
        return;
    }

    const int lane = tid & 63, wv = tid >> 6;
    const int widx = bid * 4 + wv;               // 0..3071
    const int m0 = (widx & 63) * 16, n0 = (widx >> 6) * 16;
    const int r = lane & 15, q = lane >> 4;

    const float* ap = x + (size_t)(m0 + r) * DM + q * 8;
    const float* bp = W + (size_t)(q * 8) * 768 + n0 + r;

    f32x4 acc = {0.f, 0.f, 0.f, 0.f};
    #pragma unroll
    for (int kt = 0; kt < DM; kt += 32) {
        float4 a0 = *(const float4*)(ap + kt);
        float4 a1 = *(const float4*)(ap + kt + 4);
        bf16x8 af;
        af[0] = (__bf16)a0.x; af[1] = (__bf16)a0.y; af[2] = (__bf16)a0.z; af[3] = (__bf16)a0.w;
        af[4] = (__bf16)a1.x; af[5] = (__bf16)a1.y; af[6] = (__bf16)a1.z; af[7] = (__bf16)a1.w;
        bf16x8 bf;
        #pragma unroll
        for (int j = 0; j < 8; ++j)
            bf[j] = (__bf16)bp[(size_t)(kt + j) * 768];
        acc = __builtin_amdgcn_mfma_f32_16x16x32_bf16(af, bf, acc, 0, 0, 0);
    }

    __half*  qh  = (__half*)(wsb + B_QH);
    __half*  kh  = (__half*)(wsb + B_KH);
    __bf16*  vtb = (__bf16*)(wsb + B_VT);
    const int n = n0 + r;                 // C col = lane&15
    const float bn = bias[n];
    const int h = n / 96, jj = n % 96;
    #pragma unroll
    for (int i = 0; i < 4; ++i) {
        const int m = m0 + q * 4 + i;     // C row = q*4 + i
        const float v = acc[i] + bn;
        const int b = m >> 9, t = m & 511;
        const int bh = b * NH + h;
        if (jj < 32)      qh[((size_t)(bh * SEQ + t)) * HC + jj]        = (__half)v;
        else if (jj < 64) kh[((size_t)(bh * SEQ + t)) * HC + (jj - 32)] = (__half)v;
        else              vtb[((size_t)(bh * HC + (jj - 64))) * SEQ + t] = (__bf16)v;
    }
}

// ---------------------------------------------------------------------------
// K2: L1-distance attention + residual, fp16-packed distance (round-6 proven)
// + pre-initializes out = x1 + bproj (base for K3's atomic partials).
// ---------------------------------------------------------------------------
#define QT 16
#define PSTRIDE 514

__global__ __launch_bounds__(512, 4)
void attn_k(const char* __restrict__ wsb, const float* __restrict__ xin,
            float* __restrict__ x1, const float* __restrict__ bproj,
            float* __restrict__ out)
{
    __shared__ __half2 qtile[QT * 16];
    __shared__ __bf16  pmat[QT * PSTRIDE];
    __shared__ float   psum[QT * 8];
    __shared__ float   pinv[QT];

    const __half*  qhg = (const __half*)(wsb + B_QH);
    const __half*  khg = (const __half*)(wsb + B_KH);
    const __bf16*  vtb = (const __bf16*)(wsb + B_VT);

    const int tid  = threadIdx.x;
    const int lane = tid & 63;
    const int wv   = tid >> 6;
    const int sg   = tid;                       // s index
    const int bh   = blockIdx.x >> 5;
    const int qbase = (blockIdx.x & 31) * QT;
    const float scale = 0.17677669529663687f;   // 1/sqrt(32)

    const __half2* kp = (const __half2*)(khg + ((size_t)(bh * SEQ + sg)) * HC);
    __half2 kr[16];
    #pragma unroll
    for (int j = 0; j < 16; ++j) kr[j] = kp[j];

    if (tid < 256) {
        const int t = tid >> 4, j = tid & 15;
        qtile[t * 16 + j] =
            *(const __half2*)(qhg + ((size_t)(bh * SEQ + qbase + t)) * HC + j * 2);
    }
    __syncthreads();

    #pragma unroll 4
    for (int t = 0; t < QT; ++t) {
        __half2 acc2 = __floats2half2_rn(0.f, 0.f);
        #pragma unroll
        for (int j = 0; j < 16; ++j) {
            __half2 dif = __hsub2(kr[j], qtile[t * 16 + j]);   // LDS broadcast
            unsigned u = (*(unsigned*)&dif) & 0x7FFF7FFFu;     // packed |.|
            acc2 = __hadd2(acc2, *(__half2*)&u);
        }
        const float d = __low2float(acc2) + __high2float(acc2);
        float w = 1.0f / (0.001f + d * scale);
        if (sg == qbase + t) w = 0.0f;          // diagonal
        float p = __expf(w);                    // w bounded: no max pass
        float se = p;
        #pragma unroll
        for (int off = 32; off >= 1; off >>= 1) se += __shfl_xor(se, off, 64);
        pmat[t * PSTRIDE + sg] = (__bf16)p;
        if (lane == 0) psum[t * 8 + wv] = se;
    }
    __syncthreads();

    if (tid < QT) {
        float s = 0.f;
        #pragma unroll
        for (int j = 0; j < 8; ++j) s += psum[tid * 8 + j];
        pinv[tid] = 1.0f / s;
    }
    __syncthreads();

    if (wv < 2) {
        const int r = lane & 15, q = lane >> 4;
        const __bf16* bp  = vtb + ((size_t)(bh * HC + wv * 16 + r)) * SEQ + q * 8;
        const __bf16* apm = &pmat[r * PSTRIDE + q * 8];
        f32x4 acc = {0.f, 0.f, 0.f, 0.f};
        #pragma unroll
        for (int kt = 0; kt < SEQ; kt += 32) {
            bf16x8 af = *(const bf16x8*)(apm + kt);
            bf16x8 bf = *(const bf16x8*)(bp + kt);
            acc = __builtin_amdgcn_mfma_f32_16x16x32_bf16(af, bf, acc, 0, 0, 0);
        }
        const int b = bh >> 3, hh = bh & 7;
        const int c = wv * 16 + r;
        const int col = hh * HC + c;
        const float bpn = bproj[col];
        #pragma unroll
        for (int i = 0; i < 4; ++i) {
            const int tl = q * 4 + i;
            const int t  = qbase + tl;
            const float v = acc[i] * pinv[tl];
            const int idx = ((b * SEQ + t) * DM) + col;
            const float res = xin[idx] + v;
            x1[idx]  = res;
            out[idx] = res + bpn;      // base: x1 + bproj; K3 atomically adds h@Wproj
        }
    }
}

// ---------------------------------------------------------------------------
// K3: fused MLP, grid-preserving split-K (round-8 proven). 256 blocks x 256 thr:
// block = (m-tile mt = bid&63, slab ns = bid>>6). FC computes h-slab
// h[16][ns*256..+256) -> LDS bf16 [16][264]; PROJ computes the k-slice
// partial h_slab @ Wproj[:, ns*256..+256) and atomicAdds into out.
// ---------------------------------------------------------------------------
#define HSTR 264

__global__ __launch_bounds__(256)
void mlp_k(const float* __restrict__ X1, const char* __restrict__ wsb,
           const float* __restrict__ bfc, float* __restrict__ out)
{
    __shared__ __bf16 hs[16 * HSTR];   // 8.4 KB
    const __bf16* Wf = (const __bf16*)(wsb + B_WFCT);
    const __bf16* Wp = (const __bf16*)(wsb + B_WPJT);

    const int tid  = threadIdx.x;
    const int lane = tid & 63;
    const int wv   = tid >> 6;
    const int mt   = blockIdx.x & 63;
    const int ns   = blockIdx.x >> 6;            // k/n slab 0..3
    const int m0   = mt * 16;
    const int r    = lane & 15, q = lane >> 4;

    // ---- FC phase: h[16][ns*256 .. +256) ----
    {
        const float* ap = X1 + (size_t)(m0 + r) * DM + q * 8;
        f32x4 acc[4] = {};
        #pragma unroll
        for (int kt = 0; kt < DM; kt += 32) {
            float4 a0 = *(const float4*)(ap + kt);
            float4 a1 = *(const float4*)(ap + kt + 4);
            bf16x8 af;
            af[0] = (__bf16)a0.x; af[1] = (__bf16)a0.y; af[2] = (__bf16)a0.z; af[3] = (__bf16)a0.w;
            af[4] = (__bf16)a1.x; af[5] = (__bf16)a1.y; af[6] = (__bf16)a1.z; af[7] = (__bf16)a1.w;
            #pragma unroll
            for (int nt = 0; nt < 4; ++nt) {
                const int n0 = ns * 256 + (wv * 4 + nt) * 16;       // global h col
                bf16x8 bf = *(const bf16x8*)(Wf + (size_t)(n0 + r) * DM + q * 8 + kt);
                acc[nt] = __builtin_amdgcn_mfma_f32_16x16x32_bf16(af, bf, acc[nt], 0, 0, 0);
            }
        }
        #pragma unroll
        for (int nt = 0; nt < 4; ++nt) {
            const int nl = (wv * 4 + nt) * 16 + r;                  // local 0..255
            const float bn = bfc[ns * 256 + nl];
            #pragma unroll
            for (int i = 0; i < 4; ++i)
                hs[(q * 4 + i) * HSTR + nl] = (__bf16)qgelu(acc[nt][i] + bn);
        }
    }
    __syncthreads();

    // ---- PROJ phase: out[m0..+16][wv*64..+64) += h_slab @ Wp k-slice ----
    {
        f32x4 acc[4] = {};
        const __bf16* al = &hs[r * HSTR + q * 8];                   // A row = m
        #pragma unroll
        for (int kt = 0; kt < 256; kt += 32) {
            bf16x8 af = *(const bf16x8*)(al + kt);
            #pragma unroll
            for (int nt = 0; nt < 4; ++nt) {
                const int n0 = wv * 64 + nt * 16;
                bf16x8 bf = *(const bf16x8*)(Wp + (size_t)(n0 + r) * 1024 +
                                             ns * 256 + q * 8 + kt);
                acc[nt] = __builtin_amdgcn_mfma_f32_16x16x32_bf16(af, bf, acc[nt], 0, 0, 0);
            }
        }
        #pragma unroll
        for (int nt = 0; nt < 4; ++nt) {
            const int n = wv * 64 + nt * 16 + r;
            #pragma unroll
            for (int i = 0; i < 4; ++i) {
                const int m = m0 + q * 4 + i;
                atomicAdd(&out[(size_t)m * DM + n], acc[nt][i]);
            }
        }
    }
}

// ---------------------------------------------------------------------------
extern "C" void kernel_launch(void* const* d_in, const int* in_sizes, int n_in,
                              void* d_out, int out_size, void* d_ws, size_t ws_size,
                              hipStream_t stream)
{
    (void)in_sizes; (void)n_in; (void)out_size; (void)ws_size;
    const float* x     = (const float*)d_in[0];
    const float* Wqkv  = (const float*)d_in[1];
    const float* bqkv  = (const float*)d_in[2];
    const float* Wfc   = (const float*)d_in[3];
    const float* bfc   = (const float*)d_in[4];
    const float* Wproj = (const float*)d_in[5];
    const float* bproj = (const float*)d_in[6];
    float* out = (float*)d_out;
    char*  wsb = (char*)d_ws;
    float* x1  = (float*)(wsb + B_X1);

    // K1: QKV GEMM (strided W) + side-car Wfc/Wproj transposes
    qkv_k<<<896, 256, 0, stream>>>(x, Wqkv, bqkv, Wfc, Wproj, wsb);

    // K2: attention + residual -> x1; pre-init out = x1 + bproj
    attn_k<<<512, 512, 0, stream>>>(wsb, x, x1, bproj, out);

    // K3: out += qgelu(x1@Wfc+b) @ Wproj   (split-K x4, atomic accumulate)
    mlp_k<<<256, 256, 0, stream>>>(x1, wsb, bfc, out);
}